// Round 1
// baseline (3615.769 us; speedup 1.0000x reference)
//
#include <hip/hip_runtime.h>
#include <cstdint>
#include <cstddef>

// Problem dims (fixed)
#define T_DIM 2048
#define D_DIM 2048
#define HI_N 4
#define DI_N 64
#define H_N 16
#define DH_N 128
#define TOPK_N 512
#define NEG_F (-1e9f)

// ---------------------------------------------------------------------------
// Generic tiled fp32 GEMM: C[M,N] = A[M,K] @ B[K,N], all row-major.
// 64x64 tile, BK=16, 256 threads, 4x4 acc per thread.
// M, K assumed multiples of 64/16 (true here: M=2048, K=2048). N guarded.
// ---------------------------------------------------------------------------
__global__ __launch_bounds__(256) void gemm_f32(const float* __restrict__ A,
                                                const float* __restrict__ B,
                                                float* __restrict__ C,
                                                int M, int N, int K) {
  __shared__ float As[16][64];
  __shared__ float Bs[16][64];
  const int bm = blockIdx.y << 6;
  const int bn = blockIdx.x << 6;
  const int tid = threadIdx.x;
  const int tx = tid & 15;
  const int ty = tid >> 4;
  float acc[4][4] = {};
  for (int k0 = 0; k0 < K; k0 += 16) {
#pragma unroll
    for (int i = 0; i < 4; ++i) {
      int e = tid + (i << 8);          // [0,1024)
      int m = e >> 4, kk = e & 15;     // A[bm+m][k0+kk]: consecutive kk -> coalesced
      As[kk][m] = A[(size_t)(bm + m) * K + (k0 + kk)];
    }
#pragma unroll
    for (int i = 0; i < 4; ++i) {
      int e = tid + (i << 8);
      int kk = e >> 6, n = e & 63;     // B[k0+kk][bn+n]: consecutive n -> coalesced
      int gn = bn + n;
      Bs[kk][n] = (gn < N) ? B[(size_t)(k0 + kk) * N + gn] : 0.f;
    }
    __syncthreads();
#pragma unroll
    for (int kk = 0; kk < 16; ++kk) {
      float4 a4 = *(const float4*)&As[kk][ty << 2];
      float4 b4 = *(const float4*)&Bs[kk][tx << 2];
      float av[4] = {a4.x, a4.y, a4.z, a4.w};
      float bv[4] = {b4.x, b4.y, b4.z, b4.w};
#pragma unroll
      for (int i = 0; i < 4; ++i)
#pragma unroll
        for (int j = 0; j < 4; ++j) acc[i][j] += av[i] * bv[j];
    }
    __syncthreads();
  }
#pragma unroll
  for (int i = 0; i < 4; ++i) {
    int m = bm + (ty << 2) + i;
    int n0 = bn + (tx << 2);
    if (n0 + 3 < N) {
      *(float4*)&C[(size_t)m * N + n0] =
          make_float4(acc[i][0], acc[i][1], acc[i][2], acc[i][3]);
    } else {
#pragma unroll
      for (int j = 0; j < 4; ++j)
        if (n0 + j < N) C[(size_t)m * N + n0 + j] = acc[i][j];
    }
  }
}

// ---------------------------------------------------------------------------
// Lightning indexer scores, causal-masked:
//   out[t,s] = (s>t) ? NEG : sum_h w[t,h]*relu(qi[t,h,:].ki[s,:])
// Block = 16x16 (t,s) tile, 256 threads, one (t,s) per thread.
// ---------------------------------------------------------------------------
__global__ __launch_bounds__(256) void idx_scores(const float* __restrict__ qi,
                                                  const float* __restrict__ ki,
                                                  const float* __restrict__ w,
                                                  float* __restrict__ out) {
  __shared__ float qs[16][256];
  __shared__ float ks[16][68];  // padded: 2-way LDS aliasing only (free)
  __shared__ float wsh[16][4];
  const int t0 = blockIdx.y << 4;
  const int s0 = blockIdx.x << 4;
  const int tid = threadIdx.x;
  for (int i = tid; i < 16 * 256; i += 256) {
    int r = i >> 8, c = i & 255;
    qs[r][c] = qi[(size_t)(t0 + r) * 256 + c];
  }
  for (int i = tid; i < 16 * 64; i += 256) {
    int r = i >> 6, c = i & 63;
    ks[r][c] = ki[(size_t)(s0 + r) * 64 + c];
  }
  if (tid < 64) wsh[tid >> 2][tid & 3] = w[(size_t)(t0 + (tid >> 2)) * 4 + (tid & 3)];
  __syncthreads();
  const int ts = tid >> 4, ss = tid & 15;
  float acc = 0.f;
#pragma unroll
  for (int h = 0; h < HI_N; ++h) {
    float d = 0.f;
#pragma unroll
    for (int j = 0; j < DI_N; ++j) d += qs[ts][h * DI_N + j] * ks[ss][j];
    acc += fmaxf(d, 0.f) * wsh[ts][h];
  }
  const int t = t0 + ts, s = s0 + ss;
  out[(size_t)t * T_DIM + s] = (s > t) ? NEG_F : acc;
}

// ---------------------------------------------------------------------------
// Per-row top-512 via full bitonic sort of 2048 64-bit keys in LDS.
// Key = (monotone_f32(value) << 32) | (2047 - index): descending sort gives
// value-desc, index-asc tie-break — exactly jax.lax.top_k semantics.
// ---------------------------------------------------------------------------
__global__ __launch_bounds__(1024) void topk_rows(const float* __restrict__ scores,
                                                  int* __restrict__ top_idx) {
  __shared__ unsigned long long keys[T_DIM];
  const int t = blockIdx.x;
  const int tid = threadIdx.x;
  const float* row = scores + (size_t)t * T_DIM;
  for (int i = tid; i < T_DIM; i += 1024) {
    unsigned u = __float_as_uint(row[i]);
    u = (u & 0x80000000u) ? ~u : (u | 0x80000000u);
    keys[i] = ((unsigned long long)u << 32) | (unsigned)(T_DIM - 1 - i);
  }
  __syncthreads();
  for (int k = 2; k <= T_DIM; k <<= 1) {
    for (int j = k >> 1; j > 0; j >>= 1) {
      for (int base = tid; base < T_DIM; base += 1024) {
        int ixj = base ^ j;
        if (ixj > base) {
          unsigned long long a = keys[base], b = keys[ixj];
          bool desc = (base & k) == 0;
          if (desc ? (a < b) : (a > b)) { keys[base] = b; keys[ixj] = a; }
        }
      }
      __syncthreads();
    }
  }
  for (int i = tid; i < TOPK_N; i += 1024) {
    top_idx[(size_t)t * TOPK_N + i] = (T_DIM - 1) - (int)(keys[i] & 0xFFFFFFFFull);
  }
}

// ---------------------------------------------------------------------------
// Sparse attention: one block per (t, h). Gather 512 selected columns,
// score = q.k/sqrt(DH) (wave-per-column), softmax over 512, PV coalesced.
// ---------------------------------------------------------------------------
__global__ __launch_bounds__(256) void sparse_attn(const float* __restrict__ q,
                                                   const float* __restrict__ k,
                                                   const float* __restrict__ v,
                                                   const int* __restrict__ top_idx,
                                                   float* __restrict__ attn) {
  __shared__ float qv[DH_N];
  __shared__ float sc[TOPK_N];
  __shared__ int cols[TOPK_N];
  __shared__ float red[8];
  const int t = blockIdx.x, h = blockIdx.y;
  const int tid = threadIdx.x;
  const int wave = tid >> 6, lane = tid & 63;
  if (tid < DH_N) qv[tid] = q[(size_t)t * D_DIM + h * DH_N + tid];
  for (int i = tid; i < TOPK_N; i += 256) cols[i] = top_idx[(size_t)t * TOPK_N + i];
  __syncthreads();
  const float rsc = 0.08838834764831845f;  // 1/sqrt(128)
  // scores: each wave owns columns c = wave, wave+4, ...
  for (int c = wave; c < TOPK_N; c += 4) {
    const int s = cols[c];
    float2 kk2 = ((const float2*)(k + (size_t)s * D_DIM + h * DH_N))[lane];
    float2 qq2 = ((const float2*)qv)[lane];
    float d = kk2.x * qq2.x + kk2.y * qq2.y;
#pragma unroll
    for (int off = 32; off > 0; off >>= 1) d += __shfl_down(d, off);
    if (lane == 0) sc[c] = d * rsc;
  }
  __syncthreads();
  // block max
  float m = -1e30f;
  for (int i = tid; i < TOPK_N; i += 256) m = fmaxf(m, sc[i]);
#pragma unroll
  for (int off = 32; off > 0; off >>= 1) m = fmaxf(m, __shfl_down(m, off));
  if (lane == 0) red[wave] = m;
  __syncthreads();
  if (tid == 0) red[4] = fmaxf(fmaxf(red[0], red[1]), fmaxf(red[2], red[3]));
  __syncthreads();
  m = red[4];
  // exp + block sum
  float ssum = 0.f;
  for (int i = tid; i < TOPK_N; i += 256) {
    float e = __expf(sc[i] - m);
    sc[i] = e;
    ssum += e;
  }
#pragma unroll
  for (int off = 32; off > 0; off >>= 1) ssum += __shfl_down(ssum, off);
  if (lane == 0) red[wave] = ssum;
  __syncthreads();
  if (tid == 0) red[5] = 1.f / (red[0] + red[1] + red[2] + red[3]);
  __syncthreads();
  const float inv = red[5];
  // PV: threads 0..127 each own an output dim; v reads fully coalesced.
  if (tid < DH_N) {
    float acc = 0.f;
    for (int c = 0; c < TOPK_N; ++c) {
      acc += sc[c] * v[(size_t)cols[c] * D_DIM + h * DH_N + tid];
    }
    attn[(size_t)t * D_DIM + h * DH_N + tid] = acc * inv;
  }
}

// ---------------------------------------------------------------------------
extern "C" void kernel_launch(void* const* d_in, const int* in_sizes, int n_in,
                              void* d_out, int out_size, void* d_ws, size_t ws_size,
                              hipStream_t stream) {
  (void)in_sizes; (void)n_in; (void)out_size; (void)ws_size;
  const float* x      = (const float*)d_in[0];
  const float* Wq_idx = (const float*)d_in[1];
  const float* Wk_idx = (const float*)d_in[2];
  const float* Ww_idx = (const float*)d_in[3];
  const float* Wq     = (const float*)d_in[4];
  const float* Wk     = (const float*)d_in[5];
  const float* Wv     = (const float*)d_in[6];
  const float* Wo     = (const float*)d_in[7];
  float* out = (float*)d_out;

  char* ws = (char*)d_ws;
  const size_t MB = 1ull << 20;
  // Aliased layout (peak 68 MB):
  //   [0,4)    top_idx (persistent)
  //   [4,20)   scores  -> reused as q after topk
  //   [20,36)  qi/ki/w -> overwritten by k after idx_scores
  //   [36,52)  v
  //   [52,68)  attn
  int*   top_idx = (int*)(ws);
  float* scores  = (float*)(ws + 4 * MB);
  float* q       = (float*)(ws + 4 * MB);
  float* qi      = (float*)(ws + 20 * MB);
  float* ki      = (float*)(ws + 22 * MB);
  float* wI      = (float*)(ws + 22 * MB + 512 * 1024);
  float* k       = (float*)(ws + 20 * MB);
  float* v       = (float*)(ws + 36 * MB);
  float* attn    = (float*)(ws + 52 * MB);

  const dim3 blk(256);
  // 1) indexer projections
  gemm_f32<<<dim3(256 / 64, T_DIM / 64), blk, 0, stream>>>(x, Wq_idx, qi, T_DIM, HI_N * DI_N, D_DIM);
  gemm_f32<<<dim3(1, T_DIM / 64), blk, 0, stream>>>(x, Wk_idx, ki, T_DIM, DI_N, D_DIM);
  gemm_f32<<<dim3(1, T_DIM / 64), blk, 0, stream>>>(x, Ww_idx, wI, T_DIM, HI_N, D_DIM);
  // 2) index scores (causal-masked)
  idx_scores<<<dim3(T_DIM / 16, T_DIM / 16), blk, 0, stream>>>(qi, ki, wI, scores);
  // 3) top-512 per row
  topk_rows<<<dim3(T_DIM), dim3(1024), 0, stream>>>(scores, top_idx);
  // 4) q/k/v projections (q overwrites scores, k overwrites qi/ki/w — both dead)
  gemm_f32<<<dim3(D_DIM / 64, T_DIM / 64), blk, 0, stream>>>(x, Wq, q, T_DIM, D_DIM, D_DIM);
  gemm_f32<<<dim3(D_DIM / 64, T_DIM / 64), blk, 0, stream>>>(x, Wk, k, T_DIM, D_DIM, D_DIM);
  gemm_f32<<<dim3(D_DIM / 64, T_DIM / 64), blk, 0, stream>>>(x, Wv, v, T_DIM, D_DIM, D_DIM);
  // 5) sparse attention
  sparse_attn<<<dim3(T_DIM, H_N), blk, 0, stream>>>(q, k, v, top_idx, attn);
  // 6) output projection
  gemm_f32<<<dim3(D_DIM / 64, T_DIM / 64), blk, 0, stream>>>(attn, Wo, out, T_DIM, D_DIM, D_DIM);
}

// Round 2
// 1882.680 us; speedup vs baseline: 1.9205x; 1.9205x over previous
//
#include <hip/hip_runtime.h>
#include <cstdint>
#include <cstddef>

#define T_DIM 2048
#define D_DIM 2048
#define HI_N 4
#define DI_N 64
#define H_N 16
#define DH_N 128
#define TOPK_N 512
#define NEG_F (-1e9f)

typedef __attribute__((ext_vector_type(8))) short short8;
typedef __attribute__((ext_vector_type(4))) float f32x4;
typedef unsigned short ushort_t;

__device__ __forceinline__ unsigned short f2bf(float f) {
  unsigned u = __float_as_uint(f);
  u += 0x7FFFu + ((u >> 16) & 1u);   // RNE
  return (unsigned short)(u >> 16);
}
__device__ __forceinline__ float bf2f(unsigned short b) {
  return __uint_as_float((unsigned)b << 16);
}

// ---------------------------------------------------------------------------
// fp32 tiled GEMM (kept for the precision-sensitive indexer projections)
// ---------------------------------------------------------------------------
__global__ __launch_bounds__(256) void gemm_f32(const float* __restrict__ A,
                                                const float* __restrict__ B,
                                                float* __restrict__ C,
                                                int M, int N, int K) {
  __shared__ float As[16][64];
  __shared__ float Bs[16][64];
  const int bm = blockIdx.y << 6;
  const int bn = blockIdx.x << 6;
  const int tid = threadIdx.x;
  const int tx = tid & 15;
  const int ty = tid >> 4;
  float acc[4][4] = {};
  for (int k0 = 0; k0 < K; k0 += 16) {
#pragma unroll
    for (int i = 0; i < 4; ++i) {
      int e = tid + (i << 8);
      int m = e >> 4, kk = e & 15;
      As[kk][m] = A[(size_t)(bm + m) * K + (k0 + kk)];
    }
#pragma unroll
    for (int i = 0; i < 4; ++i) {
      int e = tid + (i << 8);
      int kk = e >> 6, n = e & 63;
      int gn = bn + n;
      Bs[kk][n] = (gn < N) ? B[(size_t)(k0 + kk) * N + gn] : 0.f;
    }
    __syncthreads();
#pragma unroll
    for (int kk = 0; kk < 16; ++kk) {
      float4 a4 = *(const float4*)&As[kk][ty << 2];
      float4 b4 = *(const float4*)&Bs[kk][tx << 2];
      float av[4] = {a4.x, a4.y, a4.z, a4.w};
      float bv[4] = {b4.x, b4.y, b4.z, b4.w};
#pragma unroll
      for (int i = 0; i < 4; ++i)
#pragma unroll
        for (int j = 0; j < 4; ++j) acc[i][j] += av[i] * bv[j];
    }
    __syncthreads();
  }
#pragma unroll
  for (int i = 0; i < 4; ++i) {
    int m = bm + (ty << 2) + i;
    int n0 = bn + (tx << 2);
    if (n0 + 3 < N) {
      *(float4*)&C[(size_t)m * N + n0] =
          make_float4(acc[i][0], acc[i][1], acc[i][2], acc[i][3]);
    } else {
#pragma unroll
      for (int j = 0; j < 4; ++j)
        if (n0 + j < N) C[(size_t)m * N + n0 + j] = acc[i][j];
    }
  }
}

// ---------------------------------------------------------------------------
// casts
// ---------------------------------------------------------------------------
__global__ __launch_bounds__(256) void cast_bf16(const float* __restrict__ in,
                                                 ushort_t* __restrict__ out) {
  int i = (blockIdx.x * 256 + threadIdx.x) * 4;
  float4 f = *(const float4*)(in + i);
  ushort4 o;
  o.x = f2bf(f.x); o.y = f2bf(f.y); o.z = f2bf(f.z); o.w = f2bf(f.w);
  *(ushort4*)(out + i) = o;
}

// in[R][C] f32 -> out[C][R] bf16
__global__ __launch_bounds__(256) void cast_transpose(const float* __restrict__ in,
                                                      ushort_t* __restrict__ out,
                                                      int R, int C) {
  __shared__ float tile[32][33];
  const int bx = blockIdx.x * 32;  // col base
  const int by = blockIdx.y * 32;  // row base
  const int tx = threadIdx.x & 31, ty = threadIdx.x >> 5;  // ty 0..7
#pragma unroll
  for (int i = 0; i < 32; i += 8)
    tile[ty + i][tx] = in[(size_t)(by + ty + i) * C + bx + tx];
  __syncthreads();
#pragma unroll
  for (int i = 0; i < 32; i += 8)
    out[(size_t)(bx + ty + i) * R + by + tx] = f2bf(tile[tx][ty + i]);
}

// ---------------------------------------------------------------------------
// bf16 MFMA GEMM: C[M,N] = A[M,K] @ Bt[N,K]^T (m97 structure).
// 128x128 tile, BK=64, 256 threads (4 waves 2x2), global_load_lds width 16.
// M,N multiples of 128; K multiple of 64.
// ---------------------------------------------------------------------------
template <int OUT_BF16>
__global__ __launch_bounds__(256) void gemm_bt(const ushort_t* __restrict__ A,
                                               const ushort_t* __restrict__ Bt,
                                               void* __restrict__ C,
                                               int M, int N, int K) {
  __shared__ __attribute__((aligned(16))) ushort_t As[128 * 64];
  __shared__ __attribute__((aligned(16))) ushort_t Bs[128 * 64];
  const int bm = blockIdx.y << 7;
  const int bn = blockIdx.x << 7;
  const int tid = threadIdx.x;
  const int lane = tid & 63;
  const int wv = tid >> 6;
  const int wm = (wv >> 1) << 6;  // 0 or 64
  const int wn = (wv & 1) << 6;

  f32x4 acc[4][4] = {};

  // staging source: issue i covers rows i*32..i*32+31, this thread's slice
  const int sr = tid >> 3;            // 0..31
  const int sc = (tid & 7) << 3;      // 0,8,...,56 (elements)
  const ushort_t* ga = A + (size_t)(bm + sr) * K + sc;
  const ushort_t* gb = Bt + (size_t)(bn + sr) * K + sc;
  const size_t rstep = (size_t)32 * K;

  for (int k0 = 0; k0 < K; k0 += 64) {
#pragma unroll
    for (int i = 0; i < 4; ++i) {
      __builtin_amdgcn_global_load_lds(
          (const __attribute__((address_space(1))) unsigned int*)(ga + i * rstep + k0),
          (__attribute__((address_space(3))) unsigned int*)(As + i * 2048 + tid * 8),
          16, 0, 0);
      __builtin_amdgcn_global_load_lds(
          (const __attribute__((address_space(1))) unsigned int*)(gb + i * rstep + k0),
          (__attribute__((address_space(3))) unsigned int*)(Bs + i * 2048 + tid * 8),
          16, 0, 0);
    }
    __syncthreads();
#pragma unroll
    for (int ks = 0; ks < 2; ++ks) {
      short8 af[4], bfr[4];
      const int kk = (ks << 5) + ((lane >> 4) << 3);
#pragma unroll
      for (int i = 0; i < 4; ++i) {
        af[i]  = *(const short8*)(As + (wm + (i << 4) + (lane & 15)) * 64 + kk);
        bfr[i] = *(const short8*)(Bs + (wn + (i << 4) + (lane & 15)) * 64 + kk);
      }
#pragma unroll
      for (int i = 0; i < 4; ++i)
#pragma unroll
        for (int j = 0; j < 4; ++j)
          acc[i][j] = __builtin_amdgcn_mfma_f32_16x16x32_bf16(af[i], bfr[j], acc[i][j], 0, 0, 0);
    }
    __syncthreads();
  }

  // epilogue: C/D layout col=lane&15, row=(lane>>4)*4+r
  const int lrow = (lane >> 4) << 2;
  const int lcol = lane & 15;
#pragma unroll
  for (int i = 0; i < 4; ++i) {
    const int row = bm + wm + (i << 4) + lrow;
#pragma unroll
    for (int j = 0; j < 4; ++j) {
      const int col = bn + wn + (j << 4) + lcol;
#pragma unroll
      for (int r = 0; r < 4; ++r) {
        if (OUT_BF16)
          ((ushort_t*)C)[(size_t)(row + r) * N + col] = f2bf(acc[i][j][r]);
        else
          ((float*)C)[(size_t)(row + r) * N + col] = acc[i][j][r];
      }
    }
  }
}

// ---------------------------------------------------------------------------
// Lightning indexer scores (fp32, unchanged — top-k selection is tie-sensitive)
// ---------------------------------------------------------------------------
__global__ __launch_bounds__(256) void idx_scores(const float* __restrict__ qi,
                                                  const float* __restrict__ ki,
                                                  const float* __restrict__ w,
                                                  float* __restrict__ out) {
  __shared__ float qs[16][256];
  __shared__ float ks[16][68];
  __shared__ float wsh[16][4];
  const int t0 = blockIdx.y << 4;
  const int s0 = blockIdx.x << 4;
  const int tid = threadIdx.x;
  for (int i = tid; i < 16 * 256; i += 256) {
    int r = i >> 8, c = i & 255;
    qs[r][c] = qi[(size_t)(t0 + r) * 256 + c];
  }
  for (int i = tid; i < 16 * 64; i += 256) {
    int r = i >> 6, c = i & 63;
    ks[r][c] = ki[(size_t)(s0 + r) * 64 + c];
  }
  if (tid < 64) wsh[tid >> 2][tid & 3] = w[(size_t)(t0 + (tid >> 2)) * 4 + (tid & 3)];
  __syncthreads();
  const int ts = tid >> 4, ss = tid & 15;
  float acc = 0.f;
#pragma unroll
  for (int h = 0; h < HI_N; ++h) {
    float d = 0.f;
#pragma unroll
    for (int j = 0; j < DI_N; ++j) d += qs[ts][h * DI_N + j] * ks[ss][j];
    acc += fmaxf(d, 0.f) * wsh[ts][h];
  }
  const int t = t0 + ts, s = s0 + ss;
  out[(size_t)t * T_DIM + s] = (s > t) ? NEG_F : acc;
}

// ---------------------------------------------------------------------------
// Per-row top-512 (bitonic, jax tie semantics) — unchanged
// ---------------------------------------------------------------------------
__global__ __launch_bounds__(1024) void topk_rows(const float* __restrict__ scores,
                                                  int* __restrict__ top_idx) {
  __shared__ unsigned long long keys[T_DIM];
  const int t = blockIdx.x;
  const int tid = threadIdx.x;
  const float* row = scores + (size_t)t * T_DIM;
  for (int i = tid; i < T_DIM; i += 1024) {
    unsigned u = __float_as_uint(row[i]);
    u = (u & 0x80000000u) ? ~u : (u | 0x80000000u);
    keys[i] = ((unsigned long long)u << 32) | (unsigned)(T_DIM - 1 - i);
  }
  __syncthreads();
  for (int k = 2; k <= T_DIM; k <<= 1) {
    for (int j = k >> 1; j > 0; j >>= 1) {
      for (int base = tid; base < T_DIM; base += 1024) {
        int ixj = base ^ j;
        if (ixj > base) {
          unsigned long long a = keys[base], b = keys[ixj];
          bool desc = (base & k) == 0;
          if (desc ? (a < b) : (a > b)) { keys[base] = b; keys[ixj] = a; }
        }
      }
      __syncthreads();
    }
  }
  for (int i = tid; i < TOPK_N; i += 1024) {
    top_idx[(size_t)t * TOPK_N + i] = (T_DIM - 1) - (int)(keys[i] & 0xFFFFFFFFull);
  }
}

// ---------------------------------------------------------------------------
// Sparse attention v2: bf16 q/k/v, thread-per-column scores, split-K PV.
// Block per (t,h), 256 threads.
// ---------------------------------------------------------------------------
__global__ __launch_bounds__(256) void sparse_attn2(const ushort_t* __restrict__ q,
                                                    const ushort_t* __restrict__ k,
                                                    const ushort_t* __restrict__ v,
                                                    const int* __restrict__ top_idx,
                                                    ushort_t* __restrict__ attn) {
  __shared__ float qf[128];
  __shared__ int cols[TOPK_N];
  __shared__ float sc[TOPK_N];
  __shared__ float red[8];
  __shared__ float pv[2][128];
  const int t = blockIdx.x, h = blockIdx.y;
  const int tid = threadIdx.x;
  const int wave = tid >> 6, lane = tid & 63;
  if (tid < 128) qf[tid] = bf2f(q[(size_t)t * D_DIM + h * DH_N + tid]);
  for (int i = tid; i < TOPK_N; i += 256) cols[i] = top_idx[(size_t)t * TOPK_N + i];
  __syncthreads();

  // ---- scores: 2 columns per thread, straight FMAs, no shuffles ----
  {
    const ushort_t* kp0 = k + (size_t)cols[tid] * D_DIM + h * DH_N;
    const ushort_t* kp1 = k + (size_t)cols[tid + 256] * D_DIM + h * DH_N;
    float s0 = 0.f, s1 = 0.f;
#pragma unroll
    for (int j = 0; j < 128; j += 8) {
      uint4 ka = *(const uint4*)(kp0 + j);
      uint4 kb = *(const uint4*)(kp1 + j);
      float4 q0 = *(const float4*)(qf + j);
      float4 q1 = *(const float4*)(qf + j + 4);
      s0 += __uint_as_float(ka.x << 16) * q0.x;
      s0 += __uint_as_float(ka.x & 0xFFFF0000u) * q0.y;
      s0 += __uint_as_float(ka.y << 16) * q0.z;
      s0 += __uint_as_float(ka.y & 0xFFFF0000u) * q0.w;
      s0 += __uint_as_float(ka.z << 16) * q1.x;
      s0 += __uint_as_float(ka.z & 0xFFFF0000u) * q1.y;
      s0 += __uint_as_float(ka.w << 16) * q1.z;
      s0 += __uint_as_float(ka.w & 0xFFFF0000u) * q1.w;
      s1 += __uint_as_float(kb.x << 16) * q0.x;
      s1 += __uint_as_float(kb.x & 0xFFFF0000u) * q0.y;
      s1 += __uint_as_float(kb.y << 16) * q0.z;
      s1 += __uint_as_float(kb.y & 0xFFFF0000u) * q0.w;
      s1 += __uint_as_float(kb.z << 16) * q1.x;
      s1 += __uint_as_float(kb.z & 0xFFFF0000u) * q1.y;
      s1 += __uint_as_float(kb.w << 16) * q1.z;
      s1 += __uint_as_float(kb.w & 0xFFFF0000u) * q1.w;
    }
    const float rsc = 0.08838834764831845f;  // 1/sqrt(128)
    sc[tid] = s0 * rsc;
    sc[tid + 256] = s1 * rsc;
  }
  __syncthreads();

  // ---- softmax over 512 ----
  float m = -1e30f;
  for (int i = tid; i < TOPK_N; i += 256) m = fmaxf(m, sc[i]);
#pragma unroll
  for (int off = 32; off > 0; off >>= 1) m = fmaxf(m, __shfl_down(m, off));
  if (lane == 0) red[wave] = m;
  __syncthreads();
  if (tid == 0) red[4] = fmaxf(fmaxf(red[0], red[1]), fmaxf(red[2], red[3]));
  __syncthreads();
  m = red[4];
  float ssum = 0.f;
  for (int i = tid; i < TOPK_N; i += 256) {
    float e = __expf(sc[i] - m);
    sc[i] = e;
    ssum += e;
  }
#pragma unroll
  for (int off = 32; off > 0; off >>= 1) ssum += __shfl_down(ssum, off);
  if (lane == 0) red[wave] = ssum;
  __syncthreads();
  if (tid == 0) red[5] = 1.f / (red[0] + red[1] + red[2] + red[3]);
  __syncthreads();
  const float inv = red[5];

  // ---- PV: split-K over 2 halves, 4-way ILP, coalesced v reads ----
  {
    const int d = tid & 127, half = tid >> 7;
    const ushort_t* vp = v + h * DH_N + d;
    float a0 = 0.f, a1 = 0.f, a2 = 0.f, a3 = 0.f;
    const int cb = half << 8;
    for (int c = cb; c < cb + 256; c += 4) {
      a0 += sc[c + 0] * bf2f(vp[(size_t)cols[c + 0] * D_DIM]);
      a1 += sc[c + 1] * bf2f(vp[(size_t)cols[c + 1] * D_DIM]);
      a2 += sc[c + 2] * bf2f(vp[(size_t)cols[c + 2] * D_DIM]);
      a3 += sc[c + 3] * bf2f(vp[(size_t)cols[c + 3] * D_DIM]);
    }
    pv[half][d] = (a0 + a1) + (a2 + a3);
  }
  __syncthreads();
  if (tid < 128)
    attn[(size_t)t * D_DIM + h * DH_N + tid] = f2bf((pv[0][tid] + pv[1][tid]) * inv);
}

// ---------------------------------------------------------------------------
extern "C" void kernel_launch(void* const* d_in, const int* in_sizes, int n_in,
                              void* d_out, int out_size, void* d_ws, size_t ws_size,
                              hipStream_t stream) {
  (void)in_sizes; (void)n_in; (void)out_size; (void)ws_size;
  const float* x      = (const float*)d_in[0];
  const float* Wq_idx = (const float*)d_in[1];
  const float* Wk_idx = (const float*)d_in[2];
  const float* Ww_idx = (const float*)d_in[3];
  const float* Wq     = (const float*)d_in[4];
  const float* Wk     = (const float*)d_in[5];
  const float* Wv     = (const float*)d_in[6];
  const float* Wo     = (const float*)d_in[7];
  float* out = (float*)d_out;

  char* ws = (char*)d_ws;
  const size_t MB = 1ull << 20;
  // layout (peak ~71 MB):
  //   [0,4)    top_idx
  //   [4,20)   scores f32 -> after topk: q_bf [4,12), k_bf [12,20)
  //   [20,28)  x_bf
  //   [28,36)  Wq_t -> reused as attn_bf after q GEMM
  //   [36,44)  Wk_t
  //   [44,52)  Wv_t
  //   [52,60)  Wo_t
  //   [60,68)  v_bf
  //   [68,70)  qi f32
  //   [70,70.5) ki f32 ; [70.5,+32K) wI f32
  int*      top_idx = (int*)(ws);
  float*    scores  = (float*)(ws + 4 * MB);
  ushort_t* q_bf    = (ushort_t*)(ws + 4 * MB);
  ushort_t* k_bf    = (ushort_t*)(ws + 12 * MB);
  ushort_t* x_bf    = (ushort_t*)(ws + 20 * MB);
  ushort_t* Wq_t    = (ushort_t*)(ws + 28 * MB);
  ushort_t* attn_bf = (ushort_t*)(ws + 28 * MB);
  ushort_t* Wk_t    = (ushort_t*)(ws + 36 * MB);
  ushort_t* Wv_t    = (ushort_t*)(ws + 44 * MB);
  ushort_t* Wo_t    = (ushort_t*)(ws + 52 * MB);
  ushort_t* v_bf    = (ushort_t*)(ws + 60 * MB);
  float*    qi      = (float*)(ws + 68 * MB);
  float*    ki      = (float*)(ws + 70 * MB);
  float*    wI      = (float*)(ws + 70 * MB + 512 * 1024);

  const dim3 blk(256);
  const dim3 tgrid(D_DIM / 32, D_DIM / 32);

  // casts
  cast_bf16<<<dim3((D_DIM * T_DIM) / 1024), blk, 0, stream>>>(x, x_bf);
  cast_transpose<<<tgrid, blk, 0, stream>>>(Wq, Wq_t, D_DIM, D_DIM);
  cast_transpose<<<tgrid, blk, 0, stream>>>(Wk, Wk_t, D_DIM, D_DIM);
  cast_transpose<<<tgrid, blk, 0, stream>>>(Wv, Wv_t, D_DIM, D_DIM);
  cast_transpose<<<tgrid, blk, 0, stream>>>(Wo, Wo_t, D_DIM, D_DIM);

  // indexer path (fp32 — selection stability)
  gemm_f32<<<dim3(256 / 64, T_DIM / 64), blk, 0, stream>>>(x, Wq_idx, qi, T_DIM, HI_N * DI_N, D_DIM);
  gemm_f32<<<dim3(1, T_DIM / 64), blk, 0, stream>>>(x, Wk_idx, ki, T_DIM, DI_N, D_DIM);
  gemm_f32<<<dim3(1, T_DIM / 64), blk, 0, stream>>>(x, Ww_idx, wI, T_DIM, HI_N, D_DIM);
  idx_scores<<<dim3(T_DIM / 16, T_DIM / 16), blk, 0, stream>>>(qi, ki, wI, scores);
  topk_rows<<<dim3(T_DIM), dim3(1024), 0, stream>>>(scores, top_idx);

  // qkv projections (bf16 MFMA), q overwrites scores (dead after topk)
  const dim3 ggrid(D_DIM / 128, T_DIM / 128);
  gemm_bt<1><<<ggrid, blk, 0, stream>>>(x_bf, Wq_t, q_bf, T_DIM, D_DIM, D_DIM);
  gemm_bt<1><<<ggrid, blk, 0, stream>>>(x_bf, Wk_t, k_bf, T_DIM, D_DIM, D_DIM);
  gemm_bt<1><<<ggrid, blk, 0, stream>>>(x_bf, Wv_t, v_bf, T_DIM, D_DIM, D_DIM);

  // sparse attention (attn_bf overwrites Wq_t — dead after q GEMM)
  sparse_attn2<<<dim3(T_DIM, H_N), blk, 0, stream>>>(q_bf, k_bf, v_bf, top_idx, attn_bf);

  // output projection -> f32 out
  gemm_bt<0><<<ggrid, blk, 0, stream>>>(attn_bf, Wo_t, out, T_DIM, D_DIM, D_DIM);
}

// Round 3
// 1184.717 us; speedup vs baseline: 3.0520x; 1.5891x over previous
//
#include <hip/hip_runtime.h>
#include <cstdint>
#include <cstddef>

#define T_DIM 2048
#define D_DIM 2048
#define HI_N 4
#define DI_N 64
#define H_N 16
#define DH_N 128
#define TOPK_N 512
#define NEG_F (-1e9f)
#define FA_NEG (-1e30f)

typedef __attribute__((ext_vector_type(8))) short short8;
typedef __attribute__((ext_vector_type(4))) float f32x4;
typedef unsigned short ushort_t;

__device__ __forceinline__ unsigned short f2bf(float f) {
  unsigned u = __float_as_uint(f);
  u += 0x7FFFu + ((u >> 16) & 1u);   // RNE
  return (unsigned short)(u >> 16);
}
__device__ __forceinline__ float bf2f(unsigned short b) {
  return __uint_as_float((unsigned)b << 16);
}

// ---------------------------------------------------------------------------
// fp32 tiled GEMM (indexer projections — selection is precision-sensitive)
// ---------------------------------------------------------------------------
__global__ __launch_bounds__(256) void gemm_f32(const float* __restrict__ A,
                                                const float* __restrict__ B,
                                                float* __restrict__ C,
                                                int M, int N, int K) {
  __shared__ float As[16][64];
  __shared__ float Bs[16][64];
  const int bm = blockIdx.y << 6;
  const int bn = blockIdx.x << 6;
  const int tid = threadIdx.x;
  const int tx = tid & 15;
  const int ty = tid >> 4;
  float acc[4][4] = {};
  for (int k0 = 0; k0 < K; k0 += 16) {
#pragma unroll
    for (int i = 0; i < 4; ++i) {
      int e = tid + (i << 8);
      int m = e >> 4, kk = e & 15;
      As[kk][m] = A[(size_t)(bm + m) * K + (k0 + kk)];
    }
#pragma unroll
    for (int i = 0; i < 4; ++i) {
      int e = tid + (i << 8);
      int kk = e >> 6, n = e & 63;
      int gn = bn + n;
      Bs[kk][n] = (gn < N) ? B[(size_t)(k0 + kk) * N + gn] : 0.f;
    }
    __syncthreads();
#pragma unroll
    for (int kk = 0; kk < 16; ++kk) {
      float4 a4 = *(const float4*)&As[kk][ty << 2];
      float4 b4 = *(const float4*)&Bs[kk][tx << 2];
      float av[4] = {a4.x, a4.y, a4.z, a4.w};
      float bv[4] = {b4.x, b4.y, b4.z, b4.w};
#pragma unroll
      for (int i = 0; i < 4; ++i)
#pragma unroll
        for (int j = 0; j < 4; ++j) acc[i][j] += av[i] * bv[j];
    }
    __syncthreads();
  }
#pragma unroll
  for (int i = 0; i < 4; ++i) {
    int m = bm + (ty << 2) + i;
    int n0 = bn + (tx << 2);
    if (n0 + 3 < N) {
      *(float4*)&C[(size_t)m * N + n0] =
          make_float4(acc[i][0], acc[i][1], acc[i][2], acc[i][3]);
    } else {
#pragma unroll
      for (int j = 0; j < 4; ++j)
        if (n0 + j < N) C[(size_t)m * N + n0 + j] = acc[i][j];
    }
  }
}

// ---------------------------------------------------------------------------
// casts / transposes
// ---------------------------------------------------------------------------
__global__ __launch_bounds__(256) void cast_bf16(const float* __restrict__ in,
                                                 ushort_t* __restrict__ out) {
  int i = (blockIdx.x * 256 + threadIdx.x) * 4;
  float4 f = *(const float4*)(in + i);
  ushort4 o;
  o.x = f2bf(f.x); o.y = f2bf(f.y); o.z = f2bf(f.z); o.w = f2bf(f.w);
  *(ushort4*)(out + i) = o;
}

// in[R][C] f32 -> out[C][R] bf16
__global__ __launch_bounds__(256) void cast_transpose(const float* __restrict__ in,
                                                      ushort_t* __restrict__ out,
                                                      int R, int C) {
  __shared__ float tile[32][33];
  const int bx = blockIdx.x * 32;
  const int by = blockIdx.y * 32;
  const int tx = threadIdx.x & 31, ty = threadIdx.x >> 5;
#pragma unroll
  for (int i = 0; i < 32; i += 8)
    tile[ty + i][tx] = in[(size_t)(by + ty + i) * C + bx + tx];
  __syncthreads();
#pragma unroll
  for (int i = 0; i < 32; i += 8)
    out[(size_t)(bx + ty + i) * R + by + tx] = f2bf(tile[tx][ty + i]);
}

// bf16 [T][D] -> [D][T]
__global__ __launch_bounds__(256) void transpose_bf(const ushort_t* __restrict__ in,
                                                    ushort_t* __restrict__ out) {
  __shared__ ushort_t tile[64][68];
  const int bx = blockIdx.x * 64;  // col (D) base
  const int by = blockIdx.y * 64;  // row (T) base
  const int tid = threadIdx.x;
#pragma unroll
  for (int p = 0; p < 4; ++p) {
    int r = p * 16 + (tid >> 4), c0 = (tid & 15) * 4;
    *(ushort4*)&tile[r][c0] = *(const ushort4*)(in + (size_t)(by + r) * D_DIM + bx + c0);
  }
  __syncthreads();
#pragma unroll
  for (int p = 0; p < 4; ++p) {
    int r = p * 16 + (tid >> 4), c0 = (tid & 15) * 4;
    ushort4 o;
    o.x = tile[c0 + 0][r]; o.y = tile[c0 + 1][r];
    o.z = tile[c0 + 2][r]; o.w = tile[c0 + 3][r];
    *(ushort4*)(out + (size_t)(bx + r) * T_DIM + by + c0) = o;
  }
}

// ---------------------------------------------------------------------------
// bf16 MFMA GEMM: C[M,N] = A[M,K] @ Bt[N,K]^T (m97 structure)
// ---------------------------------------------------------------------------
template <int OUT_BF16>
__global__ __launch_bounds__(256) void gemm_bt(const ushort_t* __restrict__ A,
                                               const ushort_t* __restrict__ Bt,
                                               void* __restrict__ C,
                                               int M, int N, int K) {
  __shared__ __attribute__((aligned(16))) ushort_t As[128 * 64];
  __shared__ __attribute__((aligned(16))) ushort_t Bs[128 * 64];
  const int bm = blockIdx.y << 7;
  const int bn = blockIdx.x << 7;
  const int tid = threadIdx.x;
  const int lane = tid & 63;
  const int wv = tid >> 6;
  const int wm = (wv >> 1) << 6;
  const int wn = (wv & 1) << 6;

  f32x4 acc[4][4] = {};

  const int sr = tid >> 3;
  const int sc = (tid & 7) << 3;
  const ushort_t* ga = A + (size_t)(bm + sr) * K + sc;
  const ushort_t* gb = Bt + (size_t)(bn + sr) * K + sc;
  const size_t rstep = (size_t)32 * K;

  for (int k0 = 0; k0 < K; k0 += 64) {
#pragma unroll
    for (int i = 0; i < 4; ++i) {
      __builtin_amdgcn_global_load_lds(
          (const __attribute__((address_space(1))) unsigned int*)(ga + i * rstep + k0),
          (__attribute__((address_space(3))) unsigned int*)(As + i * 2048 + tid * 8),
          16, 0, 0);
      __builtin_amdgcn_global_load_lds(
          (const __attribute__((address_space(1))) unsigned int*)(gb + i * rstep + k0),
          (__attribute__((address_space(3))) unsigned int*)(Bs + i * 2048 + tid * 8),
          16, 0, 0);
    }
    __syncthreads();
#pragma unroll
    for (int ks = 0; ks < 2; ++ks) {
      short8 af[4], bfr[4];
      const int kk = (ks << 5) + ((lane >> 4) << 3);
#pragma unroll
      for (int i = 0; i < 4; ++i) {
        af[i]  = *(const short8*)(As + (wm + (i << 4) + (lane & 15)) * 64 + kk);
        bfr[i] = *(const short8*)(Bs + (wn + (i << 4) + (lane & 15)) * 64 + kk);
      }
#pragma unroll
      for (int i = 0; i < 4; ++i)
#pragma unroll
        for (int j = 0; j < 4; ++j)
          acc[i][j] = __builtin_amdgcn_mfma_f32_16x16x32_bf16(af[i], bfr[j], acc[i][j], 0, 0, 0);
    }
    __syncthreads();
  }

  const int lrow = (lane >> 4) << 2;
  const int lcol = lane & 15;
#pragma unroll
  for (int i = 0; i < 4; ++i) {
    const int row = bm + wm + (i << 4) + lrow;
#pragma unroll
    for (int j = 0; j < 4; ++j) {
      const int col = bn + wn + (j << 4) + lcol;
#pragma unroll
      for (int r = 0; r < 4; ++r) {
        if (OUT_BF16)
          ((ushort_t*)C)[(size_t)(row + r) * N + col] = f2bf(acc[i][j][r]);
        else
          ((float*)C)[(size_t)(row + r) * N + col] = acc[i][j][r];
      }
    }
  }
}

// ---------------------------------------------------------------------------
// Lightning indexer scores, register-tiled 64x64 fp32:
//   out[t,s] = (s>t) ? NEG : sum_h w[t,h]*relu(qi[t,h,:].ki[s,:])
// ---------------------------------------------------------------------------
__global__ __launch_bounds__(256) void idx_scores_rt(const float* __restrict__ qi,
                                                     const float* __restrict__ ki,
                                                     const float* __restrict__ w,
                                                     float* __restrict__ out) {
  const int t0 = blockIdx.y << 6, s0 = blockIdx.x << 6;
  const int tid = threadIdx.x;
  const int tx = tid & 15, ty = tid >> 4;
  if (s0 > t0 + 63) {  // fully above diagonal: NEG fill (ws is poisoned!)
    const float4 nf = make_float4(NEG_F, NEG_F, NEG_F, NEG_F);
#pragma unroll
    for (int i = 0; i < 4; ++i) {
      int m = t0 + (ty << 2) + i;
      *(float4*)&out[(size_t)m * T_DIM + s0 + (tx << 2)] = nf;
    }
    return;
  }
  __shared__ float As[16][64];   // [kk][t]
  __shared__ float Bs[16][64];   // [kk][s]
  __shared__ float wsh[64][4];
  if (tid < 64) *(float4*)wsh[tid] = *(const float4*)&w[(size_t)(t0 + tid) * 4];
  float oacc[4][4] = {};
#pragma unroll
  for (int h = 0; h < HI_N; ++h) {
    float dacc[4][4] = {};
    for (int k0 = 0; k0 < DI_N; k0 += 16) {
#pragma unroll
      for (int i = 0; i < 4; ++i) {
        int e = tid + (i << 8);
        int m = e >> 4, kk = e & 15;
        As[kk][m] = qi[(size_t)(t0 + m) * 256 + h * DI_N + k0 + kk];
        Bs[kk][m] = ki[(size_t)(s0 + m) * DI_N + k0 + kk];
      }
      __syncthreads();
#pragma unroll
      for (int kk = 0; kk < 16; ++kk) {
        float4 a4 = *(const float4*)&As[kk][ty << 2];
        float4 b4 = *(const float4*)&Bs[kk][tx << 2];
        float av[4] = {a4.x, a4.y, a4.z, a4.w};
        float bv[4] = {b4.x, b4.y, b4.z, b4.w};
#pragma unroll
        for (int i = 0; i < 4; ++i)
#pragma unroll
          for (int j = 0; j < 4; ++j) dacc[i][j] += av[i] * bv[j];
      }
      __syncthreads();
    }
#pragma unroll
    for (int i = 0; i < 4; ++i) {
      float wh = wsh[(ty << 2) + i][h];
#pragma unroll
      for (int j = 0; j < 4; ++j) oacc[i][j] += fmaxf(dacc[i][j], 0.f) * wh;
    }
  }
#pragma unroll
  for (int i = 0; i < 4; ++i) {
    int m = t0 + (ty << 2) + i;
    int n0 = s0 + (tx << 2);
    float4 r;
    r.x = (n0 + 0 > m) ? NEG_F : oacc[i][0];
    r.y = (n0 + 1 > m) ? NEG_F : oacc[i][1];
    r.z = (n0 + 2 > m) ? NEG_F : oacc[i][2];
    r.w = (n0 + 3 > m) ? NEG_F : oacc[i][3];
    *(float4*)&out[(size_t)m * T_DIM + n0] = r;
  }
}

// ---------------------------------------------------------------------------
// Per-row top-512 -> bitmask. Radix-histogram select on monotone u32 keys,
// exact jax tie semantics (value desc, index asc). Block per row.
// ---------------------------------------------------------------------------
__global__ __launch_bounds__(256) void select_mask(const float* __restrict__ scores,
                                                   unsigned long long* __restrict__ maskbits) {
  const int t = blockIdx.x, tid = threadIdx.x;
  __shared__ unsigned int hist[256];
  __shared__ unsigned int s_prefix, s_krem;
  __shared__ unsigned char bytes[256];
  unsigned int uv[8];
  const float* row = scores + (size_t)t * T_DIM;
#pragma unroll
  for (int j = 0; j < 8; ++j) {
    unsigned u = __float_as_uint(row[tid * 8 + j]);
    uv[j] = (u & 0x80000000u) ? ~u : (u | 0x80000000u);
  }
  if (tid == 0) { s_prefix = 0u; s_krem = TOPK_N; }
  for (int p = 0; p < 4; ++p) {
    const int sh = 24 - 8 * p;
    hist[tid] = 0;
    __syncthreads();
    const unsigned pm = p ? (0xFFFFFFFFu << (32 - 8 * p)) : 0u;
    const unsigned prefix = s_prefix;
#pragma unroll
    for (int j = 0; j < 8; ++j)
      if ((uv[j] & pm) == prefix) atomicAdd(&hist[(uv[j] >> sh) & 255], 1u);
    __syncthreads();
    if (tid == 0) {
      unsigned krem = s_krem, cum = 0;
      int b = 255;
      for (;; --b) { cum += hist[b]; if (cum >= krem) break; }
      s_prefix = prefix | ((unsigned)b << sh);
      s_krem = krem - (cum - hist[b]);
    }
    __syncthreads();
  }
  const unsigned V = s_prefix;
  const int kr = (int)s_krem;
  // exclusive scan of ==V counts (index order) for tie-breaking
  int eqc = 0;
#pragma unroll
  for (int j = 0; j < 8; ++j) eqc += (uv[j] == V);
  __syncthreads();
  hist[tid] = (unsigned)eqc;
  __syncthreads();
  for (int off = 1; off < 256; off <<= 1) {
    int v = (int)hist[tid];
    if (tid >= off) v += (int)hist[tid - off];
    __syncthreads();
    hist[tid] = (unsigned)v;
    __syncthreads();
  }
  int run = (int)hist[tid] - eqc;
  unsigned char byte = 0;
#pragma unroll
  for (int j = 0; j < 8; ++j) {
    bool eq = (uv[j] == V);
    bool take = (uv[j] > V) || (eq && run < kr);
    run += eq;
    byte |= (unsigned char)(take ? (1u << j) : 0u);
  }
  bytes[tid] = byte;
  __syncthreads();
  if (tid < 32) {
    unsigned long long wqw = 0;
#pragma unroll
    for (int b = 0; b < 8; ++b)
      wqw |= (unsigned long long)bytes[tid * 8 + b] << (8 * b);
    maskbits[(size_t)t * 32 + tid] = wqw;
  }
}

// ---------------------------------------------------------------------------
// Flash masked attention (bf16 MFMA). Block per (t-tile=128, head).
// S = Q K^T (C-layout rows=t), online softmax with bitmask, O^T = Vt P^T.
// ---------------------------------------------------------------------------
__global__ __launch_bounds__(256, 1) void flash_attn(
    const ushort_t* __restrict__ q, const ushort_t* __restrict__ k,
    const ushort_t* __restrict__ vt, const unsigned long long* __restrict__ maskbits,
    ushort_t* __restrict__ attn) {
  __shared__ __attribute__((aligned(16))) ushort_t Ks[128 * 128];   // Q staging, then K [s][d]
  __shared__ __attribute__((aligned(16))) ushort_t Vts[128 * 128];  // Vt [d][s]
  __shared__ __attribute__((aligned(16))) ushort_t Ps[128 * 136];   // P [t][s] pad; O transpose
  __shared__ float mstate[2][128], lstate[2][128];
  __shared__ float pmax[2][128], psum[2][128];

  const int tt = blockIdx.x;
  const int h  = blockIdx.y;
  const int t0 = tt << 7;
  const int tid = threadIdx.x;
  const int lane = tid & 63;
  const int wv = tid >> 6;
  const int wm = (wv >> 1) << 6;
  const int wn = (wv & 1) << 6;
  const int l15 = lane & 15, l4 = lane >> 4;

  // stage Q -> Ks, move frags to registers
  {
    const ushort_t* gq = q + (size_t)(t0 + (tid >> 4)) * D_DIM + h * DH_N + (tid & 15) * 8;
#pragma unroll
    for (int p = 0; p < 8; ++p)
      __builtin_amdgcn_global_load_lds(
          (const __attribute__((address_space(1))) unsigned int*)(gq + (size_t)p * 16 * D_DIM),
          (__attribute__((address_space(3))) unsigned int*)(Ks + p * 2048 + tid * 8), 16, 0, 0);
  }
  __syncthreads();
  short8 qfrag[4][4];
#pragma unroll
  for (int ks = 0; ks < 4; ++ks)
#pragma unroll
    for (int i = 0; i < 4; ++i)
      qfrag[ks][i] = *(const short8*)(Ks + (wm + i * 16 + l15) * 128 + ks * 32 + l4 * 8);
  if (tid < 128) { mstate[0][tid] = -INFINITY; lstate[0][tid] = 0.f; }

  f32x4 acc[4][4] = {};
  const int nst = (tt < 4) ? 4 : (tt + 1);
  const bool owner = ((wv & 1) == 0) && (l15 == 0);
  const float rsc = 0.08838834764831845f;  // 1/sqrt(128)

  for (int st = 0; st < nst; ++st) {
    const int s0 = st << 7;
    __syncthreads();  // prev Ks/Vts/Ps reads done (st=0: Q frags read, state init)
    {
      const ushort_t* gk = k + (size_t)(s0 + (tid >> 4)) * D_DIM + h * DH_N + (tid & 15) * 8;
      const ushort_t* gv = vt + (size_t)(h * DH_N + (tid >> 4)) * D_DIM + s0 + (tid & 15) * 8;
#pragma unroll
      for (int p = 0; p < 8; ++p) {
        __builtin_amdgcn_global_load_lds(
            (const __attribute__((address_space(1))) unsigned int*)(gk + (size_t)p * 16 * D_DIM),
            (__attribute__((address_space(3))) unsigned int*)(Ks + p * 2048 + tid * 8), 16, 0, 0);
        __builtin_amdgcn_global_load_lds(
            (const __attribute__((address_space(1))) unsigned int*)(gv + (size_t)p * 16 * D_DIM),
            (__attribute__((address_space(3))) unsigned int*)(Vts + p * 2048 + tid * 8), 16, 0, 0);
      }
    }
    // mask words (one u64 per covered row; overlaps load latency)
    unsigned long long mw[4][4];
    {
      const int wbase = (s0 >> 6) + (wn >> 6);
#pragma unroll
      for (int i = 0; i < 4; ++i)
#pragma unroll
        for (int r = 0; r < 4; ++r)
          mw[i][r] = maskbits[(size_t)(t0 + wm + i * 16 + l4 * 4 + r) * 32 + wbase];
    }
    __syncthreads();  // K/Vt landed

    // ---- S = Q K^T ----
    f32x4 sacc[4][4] = {};
#pragma unroll
    for (int ks = 0; ks < 4; ++ks) {
      short8 bfr[4];
#pragma unroll
      for (int j = 0; j < 4; ++j)
        bfr[j] = *(const short8*)(Ks + (wn + j * 16 + l15) * 128 + ks * 32 + l4 * 8);
#pragma unroll
      for (int i = 0; i < 4; ++i)
#pragma unroll
        for (int j = 0; j < 4; ++j)
          sacc[i][j] = __builtin_amdgcn_mfma_f32_16x16x32_bf16(qfrag[ks][i], bfr[j], sacc[i][j], 0, 0, 0);
    }
    // scale + mask
#pragma unroll
    for (int i = 0; i < 4; ++i)
#pragma unroll
      for (int j = 0; j < 4; ++j)
#pragma unroll
        for (int r = 0; r < 4; ++r) {
          bool sel = (mw[i][r] >> (j * 16 + l15)) & 1;
          sacc[i][j][r] = sel ? sacc[i][j][r] * rsc : FA_NEG;
        }
    // row partial max -> LDS
    float pmx[4][4];
#pragma unroll
    for (int i = 0; i < 4; ++i)
#pragma unroll
      for (int r = 0; r < 4; ++r) {
        float m0 = fmaxf(fmaxf(sacc[i][0][r], sacc[i][1][r]), fmaxf(sacc[i][2][r], sacc[i][3][r]));
#pragma unroll
        for (int off = 1; off < 16; off <<= 1) m0 = fmaxf(m0, __shfl_xor(m0, off));
        pmx[i][r] = m0;
      }
    if (l15 == 0)
#pragma unroll
      for (int i = 0; i < 4; ++i)
#pragma unroll
        for (int r = 0; r < 4; ++r)
          pmax[wv & 1][wm + i * 16 + l4 * 4 + r] = pmx[i][r];
    __syncthreads();

    const int rp = st & 1, wp = 1 - rp;
    float nmr[4][4];
#pragma unroll
    for (int i = 0; i < 4; ++i)
#pragma unroll
      for (int r = 0; r < 4; ++r) {
        int rw = wm + i * 16 + l4 * 4 + r;
        nmr[i][r] = fmaxf(mstate[rp][rw], fmaxf(pmax[0][rw], pmax[1][rw]));
      }
    float alpha_c[4];
#pragma unroll
    for (int j = 0; j < 4; ++j) {
      int col = wn + j * 16 + l15;
      float mo = mstate[rp][col];
      float nc = fmaxf(mo, fmaxf(pmax[0][col], pmax[1][col]));
      alpha_c[j] = __expf(mo - nc);
    }
    if (owner)
#pragma unroll
      for (int i = 0; i < 4; ++i)
#pragma unroll
        for (int r = 0; r < 4; ++r)
          mstate[wp][wm + i * 16 + l4 * 4 + r] = nmr[i][r];

    // P = exp(S - nm) (0 where masked), row sums, Ps write, O rescale
    float psr[4][4] = {};
#pragma unroll
    for (int i = 0; i < 4; ++i)
#pragma unroll
      for (int j = 0; j < 4; ++j)
#pragma unroll
        for (int r = 0; r < 4; ++r) {
          float s = sacc[i][j][r];
          float pv = (s <= -1e29f) ? 0.f : __expf(s - nmr[i][r]);
          sacc[i][j][r] = pv;
          psr[i][r] += pv;
        }
#pragma unroll
    for (int i = 0; i < 4; ++i)
#pragma unroll
      for (int j = 0; j < 4; ++j) {
        int col = wn + j * 16 + l15;
#pragma unroll
        for (int r = 0; r < 4; ++r)
          Ps[(wm + i * 16 + l4 * 4 + r) * 136 + col] = f2bf(sacc[i][j][r]);
      }
#pragma unroll
    for (int i = 0; i < 4; ++i)
#pragma unroll
      for (int r = 0; r < 4; ++r) {
        float sv = psr[i][r];
#pragma unroll
        for (int off = 1; off < 16; off <<= 1) sv += __shfl_xor(sv, off);
        psr[i][r] = sv;
      }
    if (l15 == 0)
#pragma unroll
      for (int i = 0; i < 4; ++i)
#pragma unroll
        for (int r = 0; r < 4; ++r)
          psum[wv & 1][wm + i * 16 + l4 * 4 + r] = psr[i][r];
#pragma unroll
    for (int i = 0; i < 4; ++i)
#pragma unroll
      for (int j = 0; j < 4; ++j)
#pragma unroll
        for (int r = 0; r < 4; ++r)
          acc[i][j][r] *= alpha_c[j];
    __syncthreads();  // Ps + psum visible

    if (owner)
#pragma unroll
      for (int i = 0; i < 4; ++i)
#pragma unroll
        for (int r = 0; r < 4; ++r) {
          int rw = wm + i * 16 + l4 * 4 + r;
          float al = __expf(mstate[rp][rw] - nmr[i][r]);
          lstate[wp][rw] = al * lstate[rp][rw] + psum[0][rw] + psum[1][rw];
        }
    // ---- O^T += Vt P^T ----
#pragma unroll
    for (int ks = 0; ks < 4; ++ks) {
      short8 af[4], bfr[4];
#pragma unroll
      for (int i = 0; i < 4; ++i)
        af[i] = *(const short8*)(Vts + (wm + i * 16 + l15) * 128 + ks * 32 + l4 * 8);
#pragma unroll
      for (int j = 0; j < 4; ++j)
        bfr[j] = *(const short8*)(Ps + (wn + j * 16 + l15) * 136 + ks * 32 + l4 * 8);
#pragma unroll
      for (int i = 0; i < 4; ++i)
#pragma unroll
        for (int j = 0; j < 4; ++j)
          acc[i][j] = __builtin_amdgcn_mfma_f32_16x16x32_bf16(af[i], bfr[j], acc[i][j], 0, 0, 0);
    }
  }
  __syncthreads();
  const int fp = nst & 1;
  float linv[4];
#pragma unroll
  for (int j = 0; j < 4; ++j) linv[j] = 1.f / lstate[fp][wn + j * 16 + l15];
  // O^T -> O via LDS (reuse Ps as [t][136])
#pragma unroll
  for (int i = 0; i < 4; ++i)
#pragma unroll
    for (int j = 0; j < 4; ++j) {
      int col = wn + j * 16 + l15;       // t
      int dbase = wm + i * 16 + l4 * 4;  // d
      ushort4 pk;
      pk.x = f2bf(acc[i][j][0] * linv[j]);
      pk.y = f2bf(acc[i][j][1] * linv[j]);
      pk.z = f2bf(acc[i][j][2] * linv[j]);
      pk.w = f2bf(acc[i][j][3] * linv[j]);
      *(ushort4*)(Ps + col * 136 + dbase) = pk;
    }
  __syncthreads();
#pragma unroll
  for (int p = 0; p < 8; ++p) {
    int rw = p * 16 + (tid >> 4);
    int d0 = (tid & 15) * 8;
    *(ulonglong2*)(attn + (size_t)(t0 + rw) * D_DIM + h * DH_N + d0) =
        *(const ulonglong2*)(Ps + rw * 136 + d0);
  }
}

// ---------------------------------------------------------------------------
extern "C" void kernel_launch(void* const* d_in, const int* in_sizes, int n_in,
                              void* d_out, int out_size, void* d_ws, size_t ws_size,
                              hipStream_t stream) {
  (void)in_sizes; (void)n_in; (void)out_size; (void)ws_size;
  const float* x      = (const float*)d_in[0];
  const float* Wq_idx = (const float*)d_in[1];
  const float* Wk_idx = (const float*)d_in[2];
  const float* Ww_idx = (const float*)d_in[3];
  const float* Wq     = (const float*)d_in[4];
  const float* Wk     = (const float*)d_in[5];
  const float* Wv     = (const float*)d_in[6];
  const float* Wo     = (const float*)d_in[7];
  float* out = (float*)d_out;

  char* ws = (char*)d_ws;
  const size_t MB = 1ull << 20;
  // layout (peak ~76 MB):
  //   [0,16)  scores f32 -> after select_mask: q_bf [0,8), k_bf [8,16)
  //   [16,16.5) maskbits
  //   [17,25)  x_bf
  //   [25,33)  Wq_t -> attn_bf after q GEMM
  //   [33,41)  Wk_t ; [41,49) Wv_t ; [49,57) Wo_t
  //   [57,65)  v_bf ; [65,73) vt_bf
  //   [73,75)  qi ; [75,75.5) ki ; then wI
  float*    scores  = (float*)(ws);
  ushort_t* q_bf    = (ushort_t*)(ws);
  ushort_t* k_bf    = (ushort_t*)(ws + 8 * MB);
  unsigned long long* maskbits = (unsigned long long*)(ws + 16 * MB);
  ushort_t* x_bf    = (ushort_t*)(ws + 17 * MB);
  ushort_t* Wq_t    = (ushort_t*)(ws + 25 * MB);
  ushort_t* attn_bf = (ushort_t*)(ws + 25 * MB);
  ushort_t* Wk_t    = (ushort_t*)(ws + 33 * MB);
  ushort_t* Wv_t    = (ushort_t*)(ws + 41 * MB);
  ushort_t* Wo_t    = (ushort_t*)(ws + 49 * MB);
  ushort_t* v_bf    = (ushort_t*)(ws + 57 * MB);
  ushort_t* vt_bf   = (ushort_t*)(ws + 65 * MB);
  float*    qi      = (float*)(ws + 73 * MB);
  float*    ki      = (float*)(ws + 75 * MB);
  float*    wI      = (float*)(ws + 75 * MB + 512 * 1024);

  const dim3 blk(256);
  const dim3 tgrid(D_DIM / 32, D_DIM / 32);

  cast_bf16<<<dim3((D_DIM * T_DIM) / 1024), blk, 0, stream>>>(x, x_bf);
  cast_transpose<<<tgrid, blk, 0, stream>>>(Wq, Wq_t, D_DIM, D_DIM);
  cast_transpose<<<tgrid, blk, 0, stream>>>(Wk, Wk_t, D_DIM, D_DIM);
  cast_transpose<<<tgrid, blk, 0, stream>>>(Wv, Wv_t, D_DIM, D_DIM);
  cast_transpose<<<tgrid, blk, 0, stream>>>(Wo, Wo_t, D_DIM, D_DIM);

  // indexer path (fp32)
  gemm_f32<<<dim3(256 / 64, T_DIM / 64), blk, 0, stream>>>(x, Wq_idx, qi, T_DIM, HI_N * DI_N, D_DIM);
  gemm_f32<<<dim3(1, T_DIM / 64), blk, 0, stream>>>(x, Wk_idx, ki, T_DIM, DI_N, D_DIM);
  gemm_f32<<<dim3(1, T_DIM / 64), blk, 0, stream>>>(x, Ww_idx, wI, T_DIM, HI_N, D_DIM);
  idx_scores_rt<<<dim3(T_DIM / 64, T_DIM / 64), blk, 0, stream>>>(qi, ki, wI, scores);
  select_mask<<<dim3(T_DIM), blk, 0, stream>>>(scores, maskbits);

  // qkv projections (scores dead -> q_bf/k_bf reuse)
  const dim3 ggrid(D_DIM / 128, T_DIM / 128);
  gemm_bt<1><<<ggrid, blk, 0, stream>>>(x_bf, Wq_t, q_bf, T_DIM, D_DIM, D_DIM);
  gemm_bt<1><<<ggrid, blk, 0, stream>>>(x_bf, Wk_t, k_bf, T_DIM, D_DIM, D_DIM);
  gemm_bt<1><<<ggrid, blk, 0, stream>>>(x_bf, Wv_t, v_bf, T_DIM, D_DIM, D_DIM);
  transpose_bf<<<dim3(D_DIM / 64, T_DIM / 64), blk, 0, stream>>>(v_bf, vt_bf);

  // flash masked attention (attn_bf overwrites Wq_t — dead)
  flash_attn<<<dim3(T_DIM / 128, H_N), blk, 0, stream>>>(q_bf, k_bf, vt_bf, maskbits, attn_bf);

  // output projection -> f32
  gemm_bt<0><<<ggrid, blk, 0, stream>>>(attn_bf, Wo_t, out, T_DIM, D_DIM, D_DIM);
}

// Round 4
// 599.092 us; speedup vs baseline: 6.0354x; 1.9775x over previous
//
#include <hip/hip_runtime.h>
#include <cstdint>
#include <cstddef>

#define T_DIM 2048
#define D_DIM 2048
#define HI_N 4
#define DI_N 64
#define H_N 16
#define DH_N 128
#define TOPK_N 512
#define NEG_F (-1e9f)
#define FA_NEG (-1e30f)

typedef __attribute__((ext_vector_type(8))) short short8;
typedef __attribute__((ext_vector_type(4))) float f32x4;
typedef unsigned short ushort_t;

__device__ __forceinline__ unsigned short f2bf(float f) {
  unsigned u = __float_as_uint(f);
  u += 0x7FFFu + ((u >> 16) & 1u);   // RNE
  return (unsigned short)(u >> 16);
}
__device__ __forceinline__ float bf2f(unsigned short b) {
  return __uint_as_float((unsigned)b << 16);
}

// ---------------------------------------------------------------------------
// Fused indexer projections (fp32): qi[2048][256], ki[2048][64], wI[2048][4].
// One dispatch, grid (6, 32): bn 0-3 -> qi col-tiles, bn 4 -> ki, bn 5 -> wI.
// Double-buffered LDS (1 barrier/iter), transpose-on-store staging (<=4-way).
// ---------------------------------------------------------------------------
__global__ __launch_bounds__(256) void idx_proj(const float* __restrict__ x,
                                                const float* __restrict__ Wq_idx,
                                                const float* __restrict__ Wk_idx,
                                                const float* __restrict__ Ww_idx,
                                                float* __restrict__ qi,
                                                float* __restrict__ ki,
                                                float* __restrict__ wI) {
  __shared__ float As[2][16][64];
  __shared__ float Bs[2][16][64];
  const int bm = blockIdx.y << 6;
  const int bn_id = blockIdx.x;
  const float* B; float* C; int ldB, cb, ncols;
  if (bn_id < 4)       { B = Wq_idx; C = qi; ldB = 256; cb = bn_id << 6; ncols = 64; }
  else if (bn_id == 4) { B = Wk_idx; C = ki; ldB = 64;  cb = 0;          ncols = 64; }
  else                 { B = Ww_idx; C = wI; ldB = 4;   cb = 0;          ncols = 4;  }
  const int tid = threadIdx.x;
  const int tx = tid & 15, ty = tid >> 4;
  const int am = tid >> 2;          // 0..63
  const int ak = (tid & 3) << 2;    // 0,4,8,12
  float acc[4][4] = {};

  // prologue: load + stage k0=0 into buf 0
  float4 a4 = *(const float4*)&x[(size_t)(bm + am) * 2048 + ak];
  float4 b4 = make_float4(0, 0, 0, 0);
  if ((tx << 2) < ncols) b4 = *(const float4*)&B[(size_t)ty * ldB + cb + (tx << 2)];
  As[0][ak + 0][am] = a4.x; As[0][ak + 1][am] = a4.y;
  As[0][ak + 2][am] = a4.z; As[0][ak + 3][am] = a4.w;
  *(float4*)&Bs[0][ty][tx << 2] = b4;

  int p = 0;
  for (int k0 = 0; k0 < 2048; k0 += 16) {
    __syncthreads();  // buf p writes visible
    const bool more = (k0 + 16) < 2048;
    if (more) {
      a4 = *(const float4*)&x[(size_t)(bm + am) * 2048 + k0 + 16 + ak];
      if ((tx << 2) < ncols)
        b4 = *(const float4*)&B[(size_t)(k0 + 16 + ty) * ldB + cb + (tx << 2)];
    }
#pragma unroll
    for (int kk = 0; kk < 16; ++kk) {
      float4 av4 = *(const float4*)&As[p][kk][ty << 2];
      float4 bv4 = *(const float4*)&Bs[p][kk][tx << 2];
      float av[4] = {av4.x, av4.y, av4.z, av4.w};
      float bv[4] = {bv4.x, bv4.y, bv4.z, bv4.w};
#pragma unroll
      for (int i = 0; i < 4; ++i)
#pragma unroll
        for (int j = 0; j < 4; ++j) acc[i][j] += av[i] * bv[j];
    }
    if (more) {
      As[1 - p][ak + 0][am] = a4.x; As[1 - p][ak + 1][am] = a4.y;
      As[1 - p][ak + 2][am] = a4.z; As[1 - p][ak + 3][am] = a4.w;
      *(float4*)&Bs[1 - p][ty][tx << 2] = b4;
    }
    p ^= 1;
  }
#pragma unroll
  for (int i = 0; i < 4; ++i) {
    int m = bm + (ty << 2) + i;
    int n0 = tx << 2;
    if (n0 + 3 < ncols) {
      *(float4*)&C[(size_t)m * ldB + cb + n0] =
          make_float4(acc[i][0], acc[i][1], acc[i][2], acc[i][3]);
    } else {
#pragma unroll
      for (int j = 0; j < 4; ++j)
        if (n0 + j < ncols) C[(size_t)m * ldB + cb + n0 + j] = acc[i][j];
    }
  }
}

// ---------------------------------------------------------------------------
// casts / transposes
// ---------------------------------------------------------------------------
__global__ __launch_bounds__(256) void cast_bf16(const float* __restrict__ in,
                                                 ushort_t* __restrict__ out) {
  int i = (blockIdx.x * 256 + threadIdx.x) * 4;
  float4 f = *(const float4*)(in + i);
  ushort4 o;
  o.x = f2bf(f.x); o.y = f2bf(f.y); o.z = f2bf(f.z); o.w = f2bf(f.w);
  *(ushort4*)(out + i) = o;
}

// in[R][C] f32 -> out[C][R] bf16
__global__ __launch_bounds__(256) void cast_transpose(const float* __restrict__ in,
                                                      ushort_t* __restrict__ out,
                                                      int R, int C) {
  __shared__ float tile[32][33];
  const int bx = blockIdx.x * 32;
  const int by = blockIdx.y * 32;
  const int tx = threadIdx.x & 31, ty = threadIdx.x >> 5;
#pragma unroll
  for (int i = 0; i < 32; i += 8)
    tile[ty + i][tx] = in[(size_t)(by + ty + i) * C + bx + tx];
  __syncthreads();
#pragma unroll
  for (int i = 0; i < 32; i += 8)
    out[(size_t)(bx + ty + i) * R + by + tx] = f2bf(tile[tx][ty + i]);
}

// bf16 [T][ldin] -> [C][T] (transpose 64x64 tiles), ldin-strided input
__global__ __launch_bounds__(256) void transpose_bf(const ushort_t* __restrict__ in,
                                                    ushort_t* __restrict__ out,
                                                    int ldin) {
  __shared__ ushort_t tile[64][68];
  const int bx = blockIdx.x * 64;  // col base (input)
  const int by = blockIdx.y * 64;  // row base (input)
  const int tid = threadIdx.x;
#pragma unroll
  for (int p = 0; p < 4; ++p) {
    int r = p * 16 + (tid >> 4), c0 = (tid & 15) * 4;
    *(ushort4*)&tile[r][c0] = *(const ushort4*)(in + (size_t)(by + r) * ldin + bx + c0);
  }
  __syncthreads();
#pragma unroll
  for (int p = 0; p < 4; ++p) {
    int r = p * 16 + (tid >> 4), c0 = (tid & 15) * 4;
    ushort4 o;
    o.x = tile[c0 + 0][r]; o.y = tile[c0 + 1][r];
    o.z = tile[c0 + 2][r]; o.w = tile[c0 + 3][r];
    *(ushort4*)(out + (size_t)(bx + r) * T_DIM + by + c0) = o;
  }
}

// ---------------------------------------------------------------------------
// bf16 MFMA GEMM: C[M,N] = A[M,K] @ Bt[N,K]^T (m97 structure)
// ---------------------------------------------------------------------------
template <int OUT_BF16>
__global__ __launch_bounds__(256) void gemm_bt(const ushort_t* __restrict__ A,
                                               const ushort_t* __restrict__ Bt,
                                               void* __restrict__ C,
                                               int M, int N, int K) {
  __shared__ __attribute__((aligned(16))) ushort_t As[128 * 64];
  __shared__ __attribute__((aligned(16))) ushort_t Bs[128 * 64];
  const int bm = blockIdx.y << 7;
  const int bn = blockIdx.x << 7;
  const int tid = threadIdx.x;
  const int lane = tid & 63;
  const int wv = tid >> 6;
  const int wm = (wv >> 1) << 6;
  const int wn = (wv & 1) << 6;

  f32x4 acc[4][4] = {};

  const int sr = tid >> 3;
  const int sc = (tid & 7) << 3;
  const ushort_t* ga = A + (size_t)(bm + sr) * K + sc;
  const ushort_t* gb = Bt + (size_t)(bn + sr) * K + sc;
  const size_t rstep = (size_t)32 * K;

  for (int k0 = 0; k0 < K; k0 += 64) {
#pragma unroll
    for (int i = 0; i < 4; ++i) {
      __builtin_amdgcn_global_load_lds(
          (const __attribute__((address_space(1))) unsigned int*)(ga + i * rstep + k0),
          (__attribute__((address_space(3))) unsigned int*)(As + i * 2048 + tid * 8),
          16, 0, 0);
      __builtin_amdgcn_global_load_lds(
          (const __attribute__((address_space(1))) unsigned int*)(gb + i * rstep + k0),
          (__attribute__((address_space(3))) unsigned int*)(Bs + i * 2048 + tid * 8),
          16, 0, 0);
    }
    __syncthreads();
#pragma unroll
    for (int ks = 0; ks < 2; ++ks) {
      short8 af[4], bfr[4];
      const int kk = (ks << 5) + ((lane >> 4) << 3);
#pragma unroll
      for (int i = 0; i < 4; ++i) {
        af[i]  = *(const short8*)(As + (wm + (i << 4) + (lane & 15)) * 64 + kk);
        bfr[i] = *(const short8*)(Bs + (wn + (i << 4) + (lane & 15)) * 64 + kk);
      }
#pragma unroll
      for (int i = 0; i < 4; ++i)
#pragma unroll
        for (int j = 0; j < 4; ++j)
          acc[i][j] = __builtin_amdgcn_mfma_f32_16x16x32_bf16(af[i], bfr[j], acc[i][j], 0, 0, 0);
    }
    __syncthreads();
  }

  const int lrow = (lane >> 4) << 2;
  const int lcol = lane & 15;
#pragma unroll
  for (int i = 0; i < 4; ++i) {
    const int row = bm + wm + (i << 4) + lrow;
#pragma unroll
    for (int j = 0; j < 4; ++j) {
      const int col = bn + wn + (j << 4) + lcol;
#pragma unroll
      for (int r = 0; r < 4; ++r) {
        if (OUT_BF16)
          ((ushort_t*)C)[(size_t)(row + r) * N + col] = f2bf(acc[i][j][r]);
        else
          ((float*)C)[(size_t)(row + r) * N + col] = acc[i][j][r];
      }
    }
  }
}

// ---------------------------------------------------------------------------
// Lightning indexer scores, register-tiled 64x64 fp32, conflict-free staging
// ---------------------------------------------------------------------------
__global__ __launch_bounds__(256) void idx_scores_rt(const float* __restrict__ qi,
                                                     const float* __restrict__ ki,
                                                     const float* __restrict__ w,
                                                     float* __restrict__ out) {
  const int t0 = blockIdx.y << 6, s0 = blockIdx.x << 6;
  const int tid = threadIdx.x;
  const int tx = tid & 15, ty = tid >> 4;
  if (s0 > t0 + 63) {  // fully above diagonal: NEG fill (ws is poisoned!)
    const float4 nf = make_float4(NEG_F, NEG_F, NEG_F, NEG_F);
#pragma unroll
    for (int i = 0; i < 4; ++i) {
      int m = t0 + (ty << 2) + i;
      *(float4*)&out[(size_t)m * T_DIM + s0 + (tx << 2)] = nf;
    }
    return;
  }
  __shared__ float As[16][64];   // [kk][t]
  __shared__ float Bs[16][64];   // [kk][s]
  __shared__ float wsh[64][4];
  if (tid < 64) *(float4*)wsh[tid] = *(const float4*)&w[(size_t)(t0 + tid) * 4];
  const int am = tid >> 2;          // 0..63
  const int ak = (tid & 3) << 2;    // 0,4,8,12
  float oacc[4][4] = {};
#pragma unroll
  for (int h = 0; h < HI_N; ++h) {
    float dacc[4][4] = {};
    for (int k0 = 0; k0 < DI_N; k0 += 16) {
      float4 qa = *(const float4*)&qi[(size_t)(t0 + am) * 256 + h * DI_N + k0 + ak];
      float4 kb = *(const float4*)&ki[(size_t)(s0 + am) * DI_N + k0 + ak];
      __syncthreads();
      As[ak + 0][am] = qa.x; As[ak + 1][am] = qa.y;
      As[ak + 2][am] = qa.z; As[ak + 3][am] = qa.w;
      Bs[ak + 0][am] = kb.x; Bs[ak + 1][am] = kb.y;
      Bs[ak + 2][am] = kb.z; Bs[ak + 3][am] = kb.w;
      __syncthreads();
#pragma unroll
      for (int kk = 0; kk < 16; ++kk) {
        float4 a4 = *(const float4*)&As[kk][ty << 2];
        float4 b4 = *(const float4*)&Bs[kk][tx << 2];
        float av[4] = {a4.x, a4.y, a4.z, a4.w};
        float bv[4] = {b4.x, b4.y, b4.z, b4.w};
#pragma unroll
        for (int i = 0; i < 4; ++i)
#pragma unroll
          for (int j = 0; j < 4; ++j) dacc[i][j] += av[i] * bv[j];
      }
    }
#pragma unroll
    for (int i = 0; i < 4; ++i) {
      float wh = wsh[(ty << 2) + i][h];
#pragma unroll
      for (int j = 0; j < 4; ++j) oacc[i][j] += fmaxf(dacc[i][j], 0.f) * wh;
    }
  }
#pragma unroll
  for (int i = 0; i < 4; ++i) {
    int m = t0 + (ty << 2) + i;
    int n0 = s0 + (tx << 2);
    float4 r;
    r.x = (n0 + 0 > m) ? NEG_F : oacc[i][0];
    r.y = (n0 + 1 > m) ? NEG_F : oacc[i][1];
    r.z = (n0 + 2 > m) ? NEG_F : oacc[i][2];
    r.w = (n0 + 3 > m) ? NEG_F : oacc[i][3];
    *(float4*)&out[(size_t)m * T_DIM + n0] = r;
  }
}

// ---------------------------------------------------------------------------
// Per-row top-512 -> bitmask. Radix-histogram select, jax tie semantics.
// ---------------------------------------------------------------------------
__global__ __launch_bounds__(256) void select_mask(const float* __restrict__ scores,
                                                   unsigned long long* __restrict__ maskbits) {
  const int t = blockIdx.x, tid = threadIdx.x;
  __shared__ unsigned int hist[256];
  __shared__ unsigned int s_prefix, s_krem;
  __shared__ unsigned char bytes[256];
  unsigned int uv[8];
  const float* row = scores + (size_t)t * T_DIM;
  {
    float4 f0 = *(const float4*)(row + tid * 8);
    float4 f1 = *(const float4*)(row + tid * 8 + 4);
    float fv[8] = {f0.x, f0.y, f0.z, f0.w, f1.x, f1.y, f1.z, f1.w};
#pragma unroll
    for (int j = 0; j < 8; ++j) {
      unsigned u = __float_as_uint(fv[j]);
      uv[j] = (u & 0x80000000u) ? ~u : (u | 0x80000000u);
    }
  }
  if (tid == 0) { s_prefix = 0u; s_krem = TOPK_N; }
  for (int p = 0; p < 4; ++p) {
    const int sh = 24 - 8 * p;
    hist[tid] = 0;
    __syncthreads();
    const unsigned pm = p ? (0xFFFFFFFFu << (32 - 8 * p)) : 0u;
    const unsigned prefix = s_prefix;
#pragma unroll
    for (int j = 0; j < 8; ++j)
      if ((uv[j] & pm) == prefix) atomicAdd(&hist[(uv[j] >> sh) & 255], 1u);
    __syncthreads();
    if (tid == 0) {
      unsigned krem = s_krem, cum = 0;
      int b = 255;
      for (;; --b) { cum += hist[b]; if (cum >= krem) break; }
      s_prefix = prefix | ((unsigned)b << sh);
      s_krem = krem - (cum - hist[b]);
    }
    __syncthreads();
  }
  const unsigned V = s_prefix;
  const int kr = (int)s_krem;
  int eqc = 0;
#pragma unroll
  for (int j = 0; j < 8; ++j) eqc += (uv[j] == V);
  __syncthreads();
  hist[tid] = (unsigned)eqc;
  __syncthreads();
  for (int off = 1; off < 256; off <<= 1) {
    int v = (int)hist[tid];
    if (tid >= off) v += (int)hist[tid - off];
    __syncthreads();
    hist[tid] = (unsigned)v;
    __syncthreads();
  }
  int run = (int)hist[tid] - eqc;
  unsigned char byte = 0;
#pragma unroll
  for (int j = 0; j < 8; ++j) {
    bool eq = (uv[j] == V);
    bool take = (uv[j] > V) || (eq && run < kr);
    run += eq;
    byte |= (unsigned char)(take ? (1u << j) : 0u);
  }
  bytes[tid] = byte;
  __syncthreads();
  if (tid < 32) {
    unsigned long long wqw = 0;
#pragma unroll
    for (int b = 0; b < 8; ++b)
      wqw |= (unsigned long long)bytes[tid * 8 + b] << (8 * b);
    maskbits[(size_t)t * 32 + tid] = wqw;
  }
}

// ---------------------------------------------------------------------------
// Flash masked attention (bf16 MFMA). Block per (t-tile=128, head).
// q/k strided (ldqk) views into fused qkv; vt dense [D][T].
// ---------------------------------------------------------------------------
__global__ __launch_bounds__(256, 1) void flash_attn(
    const ushort_t* __restrict__ q, const ushort_t* __restrict__ k,
    const ushort_t* __restrict__ vt, const unsigned long long* __restrict__ maskbits,
    ushort_t* __restrict__ attn, int ldqk) {
  __shared__ __attribute__((aligned(16))) ushort_t Ks[128 * 128];
  __shared__ __attribute__((aligned(16))) ushort_t Vts[128 * 128];
  __shared__ __attribute__((aligned(16))) ushort_t Ps[128 * 136];
  __shared__ float mstate[2][128], lstate[2][128];
  __shared__ float pmax[2][128], psum[2][128];

  const int tt = blockIdx.x;
  const int h  = blockIdx.y;
  const int t0 = tt << 7;
  const int tid = threadIdx.x;
  const int lane = tid & 63;
  const int wv = tid >> 6;
  const int wm = (wv >> 1) << 6;
  const int wn = (wv & 1) << 6;
  const int l15 = lane & 15, l4 = lane >> 4;

  {
    const ushort_t* gq = q + (size_t)(t0 + (tid >> 4)) * ldqk + h * DH_N + (tid & 15) * 8;
#pragma unroll
    for (int p = 0; p < 8; ++p)
      __builtin_amdgcn_global_load_lds(
          (const __attribute__((address_space(1))) unsigned int*)(gq + (size_t)p * 16 * ldqk),
          (__attribute__((address_space(3))) unsigned int*)(Ks + p * 2048 + tid * 8), 16, 0, 0);
  }
  __syncthreads();
  short8 qfrag[4][4];
#pragma unroll
  for (int ks = 0; ks < 4; ++ks)
#pragma unroll
    for (int i = 0; i < 4; ++i)
      qfrag[ks][i] = *(const short8*)(Ks + (wm + i * 16 + l15) * 128 + ks * 32 + l4 * 8);
  if (tid < 128) { mstate[0][tid] = -INFINITY; lstate[0][tid] = 0.f; }

  f32x4 acc[4][4] = {};
  const int nst = (tt < 4) ? 4 : (tt + 1);
  const bool owner = ((wv & 1) == 0) && (l15 == 0);
  const float rsc = 0.08838834764831845f;  // 1/sqrt(128)

  for (int st = 0; st < nst; ++st) {
    const int s0 = st << 7;
    __syncthreads();
    {
      const ushort_t* gk = k + (size_t)(s0 + (tid >> 4)) * ldqk + h * DH_N + (tid & 15) * 8;
      const ushort_t* gv = vt + (size_t)(h * DH_N + (tid >> 4)) * T_DIM + s0 + (tid & 15) * 8;
#pragma unroll
      for (int p = 0; p < 8; ++p) {
        __builtin_amdgcn_global_load_lds(
            (const __attribute__((address_space(1))) unsigned int*)(gk + (size_t)p * 16 * ldqk),
            (__attribute__((address_space(3))) unsigned int*)(Ks + p * 2048 + tid * 8), 16, 0, 0);
        __builtin_amdgcn_global_load_lds(
            (const __attribute__((address_space(1))) unsigned int*)(gv + (size_t)p * 16 * T_DIM),
            (__attribute__((address_space(3))) unsigned int*)(Vts + p * 2048 + tid * 8), 16, 0, 0);
      }
    }
    unsigned long long mw[4][4];
    {
      const int wbase = (s0 >> 6) + (wn >> 6);
#pragma unroll
      for (int i = 0; i < 4; ++i)
#pragma unroll
        for (int r = 0; r < 4; ++r)
          mw[i][r] = maskbits[(size_t)(t0 + wm + i * 16 + l4 * 4 + r) * 32 + wbase];
    }
    __syncthreads();

    f32x4 sacc[4][4] = {};
#pragma unroll
    for (int ks = 0; ks < 4; ++ks) {
      short8 bfr[4];
#pragma unroll
      for (int j = 0; j < 4; ++j)
        bfr[j] = *(const short8*)(Ks + (wn + j * 16 + l15) * 128 + ks * 32 + l4 * 8);
#pragma unroll
      for (int i = 0; i < 4; ++i)
#pragma unroll
        for (int j = 0; j < 4; ++j)
          sacc[i][j] = __builtin_amdgcn_mfma_f32_16x16x32_bf16(qfrag[ks][i], bfr[j], sacc[i][j], 0, 0, 0);
    }
#pragma unroll
    for (int i = 0; i < 4; ++i)
#pragma unroll
      for (int j = 0; j < 4; ++j)
#pragma unroll
        for (int r = 0; r < 4; ++r) {
          bool sel = (mw[i][r] >> (j * 16 + l15)) & 1;
          sacc[i][j][r] = sel ? sacc[i][j][r] * rsc : FA_NEG;
        }
    float pmx[4][4];
#pragma unroll
    for (int i = 0; i < 4; ++i)
#pragma unroll
      for (int r = 0; r < 4; ++r) {
        float m0 = fmaxf(fmaxf(sacc[i][0][r], sacc[i][1][r]), fmaxf(sacc[i][2][r], sacc[i][3][r]));
#pragma unroll
        for (int off = 1; off < 16; off <<= 1) m0 = fmaxf(m0, __shfl_xor(m0, off));
        pmx[i][r] = m0;
      }
    if (l15 == 0)
#pragma unroll
      for (int i = 0; i < 4; ++i)
#pragma unroll
        for (int r = 0; r < 4; ++r)
          pmax[wv & 1][wm + i * 16 + l4 * 4 + r] = pmx[i][r];
    __syncthreads();

    const int rp = st & 1, wp = 1 - rp;
    float nmr[4][4];
#pragma unroll
    for (int i = 0; i < 4; ++i)
#pragma unroll
      for (int r = 0; r < 4; ++r) {
        int rw = wm + i * 16 + l4 * 4 + r;
        nmr[i][r] = fmaxf(mstate[rp][rw], fmaxf(pmax[0][rw], pmax[1][rw]));
      }
    float alpha_c[4];
#pragma unroll
    for (int j = 0; j < 4; ++j) {
      int col = wn + j * 16 + l15;
      float mo = mstate[rp][col];
      float nc = fmaxf(mo, fmaxf(pmax[0][col], pmax[1][col]));
      alpha_c[j] = __expf(mo - nc);
    }
    if (owner)
#pragma unroll
      for (int i = 0; i < 4; ++i)
#pragma unroll
        for (int r = 0; r < 4; ++r)
          mstate[wp][wm + i * 16 + l4 * 4 + r] = nmr[i][r];

    float psr[4][4] = {};
#pragma unroll
    for (int i = 0; i < 4; ++i)
#pragma unroll
      for (int j = 0; j < 4; ++j)
#pragma unroll
        for (int r = 0; r < 4; ++r) {
          float s = sacc[i][j][r];
          float pv = (s <= -1e29f) ? 0.f : __expf(s - nmr[i][r]);
          sacc[i][j][r] = pv;
          psr[i][r] += pv;
        }
#pragma unroll
    for (int i = 0; i < 4; ++i)
#pragma unroll
      for (int j = 0; j < 4; ++j) {
        int col = wn + j * 16 + l15;
#pragma unroll
        for (int r = 0; r < 4; ++r)
          Ps[(wm + i * 16 + l4 * 4 + r) * 136 + col] = f2bf(sacc[i][j][r]);
      }
#pragma unroll
    for (int i = 0; i < 4; ++i)
#pragma unroll
      for (int r = 0; r < 4; ++r) {
        float sv = psr[i][r];
#pragma unroll
        for (int off = 1; off < 16; off <<= 1) sv += __shfl_xor(sv, off);
        psr[i][r] = sv;
      }
    if (l15 == 0)
#pragma unroll
      for (int i = 0; i < 4; ++i)
#pragma unroll
        for (int r = 0; r < 4; ++r)
          psum[wv & 1][wm + i * 16 + l4 * 4 + r] = psr[i][r];
#pragma unroll
    for (int i = 0; i < 4; ++i)
#pragma unroll
      for (int j = 0; j < 4; ++j)
#pragma unroll
        for (int r = 0; r < 4; ++r)
          acc[i][j][r] *= alpha_c[j];
    __syncthreads();

    if (owner)
#pragma unroll
      for (int i = 0; i < 4; ++i)
#pragma unroll
        for (int r = 0; r < 4; ++r) {
          int rw = wm + i * 16 + l4 * 4 + r;
          float al = __expf(mstate[rp][rw] - nmr[i][r]);
          lstate[wp][rw] = al * lstate[rp][rw] + psum[0][rw] + psum[1][rw];
        }
#pragma unroll
    for (int ks = 0; ks < 4; ++ks) {
      short8 af[4], bfr[4];
#pragma unroll
      for (int i = 0; i < 4; ++i)
        af[i] = *(const short8*)(Vts + (wm + i * 16 + l15) * 128 + ks * 32 + l4 * 8);
#pragma unroll
      for (int j = 0; j < 4; ++j)
        bfr[j] = *(const short8*)(Ps + (wn + j * 16 + l15) * 136 + ks * 32 + l4 * 8);
#pragma unroll
      for (int i = 0; i < 4; ++i)
#pragma unroll
        for (int j = 0; j < 4; ++j)
          acc[i][j] = __builtin_amdgcn_mfma_f32_16x16x32_bf16(af[i], bfr[j], acc[i][j], 0, 0, 0);
    }
  }
  __syncthreads();
  const int fp = nst & 1;
  float linv[4];
#pragma unroll
  for (int j = 0; j < 4; ++j) linv[j] = 1.f / lstate[fp][wn + j * 16 + l15];
#pragma unroll
  for (int i = 0; i < 4; ++i)
#pragma unroll
    for (int j = 0; j < 4; ++j) {
      int col = wn + j * 16 + l15;
      int dbase = wm + i * 16 + l4 * 4;
      ushort4 pk;
      pk.x = f2bf(acc[i][j][0] * linv[j]);
      pk.y = f2bf(acc[i][j][1] * linv[j]);
      pk.z = f2bf(acc[i][j][2] * linv[j]);
      pk.w = f2bf(acc[i][j][3] * linv[j]);
      *(ushort4*)(Ps + col * 136 + dbase) = pk;
    }
  __syncthreads();
#pragma unroll
  for (int p = 0; p < 8; ++p) {
    int rw = p * 16 + (tid >> 4);
    int d0 = (tid & 15) * 8;
    *(ulonglong2*)(attn + (size_t)(t0 + rw) * D_DIM + h * DH_N + d0) =
        *(const ulonglong2*)(Ps + rw * 136 + d0);
  }
}

// ---------------------------------------------------------------------------
extern "C" void kernel_launch(void* const* d_in, const int* in_sizes, int n_in,
                              void* d_out, int out_size, void* d_ws, size_t ws_size,
                              hipStream_t stream) {
  (void)in_sizes; (void)n_in; (void)out_size; (void)ws_size;
  const float* x      = (const float*)d_in[0];
  const float* Wq_idx = (const float*)d_in[1];
  const float* Wk_idx = (const float*)d_in[2];
  const float* Ww_idx = (const float*)d_in[3];
  const float* Wq     = (const float*)d_in[4];
  const float* Wk     = (const float*)d_in[5];
  const float* Wv     = (const float*)d_in[6];
  const float* Wo     = (const float*)d_in[7];
  float* out = (float*)d_out;

  char* ws = (char*)d_ws;
  const size_t MB = 1ull << 20;
  // layout (peak ~68.6 MB):
  //   [0,25.25)  scores f32 [0,16) early -> qkv_bf [0,25.25) after select_mask
  //   [25.5,26)  maskbits
  //   [26,34)    x_bf
  //   [34,58)    Wcat_t (Wq_t/Wk_t/Wv_t) -> vt_bf [34,42) + attn_bf [42,50) after qkv GEMM
  //   [58,66)    Wo_t
  //   [66,68)    qi ; [68,68.5) ki ; [68.5,+32K) wI
  float*    scores  = (float*)(ws);
  ushort_t* qkv_bf  = (ushort_t*)(ws);
  unsigned long long* maskbits = (unsigned long long*)(ws + 25 * MB + 512 * 1024);
  ushort_t* x_bf    = (ushort_t*)(ws + 26 * MB);
  ushort_t* Wcat_t  = (ushort_t*)(ws + 34 * MB);  // 3 x [2048][2048]
  ushort_t* vt_bf   = (ushort_t*)(ws + 34 * MB);
  ushort_t* attn_bf = (ushort_t*)(ws + 42 * MB);
  ushort_t* Wo_t    = (ushort_t*)(ws + 58 * MB);
  float*    qi      = (float*)(ws + 66 * MB);
  float*    ki      = (float*)(ws + 68 * MB);
  float*    wI      = (float*)(ws + 68 * MB + 512 * 1024);

  const dim3 blk(256);
  const dim3 tgrid(D_DIM / 32, D_DIM / 32);

  cast_bf16<<<dim3((D_DIM * T_DIM) / 1024), blk, 0, stream>>>(x, x_bf);
  cast_transpose<<<tgrid, blk, 0, stream>>>(Wq, Wcat_t, D_DIM, D_DIM);
  cast_transpose<<<tgrid, blk, 0, stream>>>(Wk, Wcat_t + (size_t)D_DIM * D_DIM, D_DIM, D_DIM);
  cast_transpose<<<tgrid, blk, 0, stream>>>(Wv, Wcat_t + (size_t)2 * D_DIM * D_DIM, D_DIM, D_DIM);
  cast_transpose<<<tgrid, blk, 0, stream>>>(Wo, Wo_t, D_DIM, D_DIM);

  // indexer path (fp32, fused projections)
  idx_proj<<<dim3(6, T_DIM / 64), blk, 0, stream>>>(x, Wq_idx, Wk_idx, Ww_idx, qi, ki, wI);
  idx_scores_rt<<<dim3(T_DIM / 64, T_DIM / 64), blk, 0, stream>>>(qi, ki, wI, scores);
  select_mask<<<dim3(T_DIM), blk, 0, stream>>>(scores, maskbits);

  // fused qkv projection: [2048][6144] = x_bf @ Wcat_t^T  (overwrites scores)
  gemm_bt<1><<<dim3(3 * D_DIM / 128, T_DIM / 128), blk, 0, stream>>>(
      x_bf, Wcat_t, qkv_bf, T_DIM, 3 * D_DIM, D_DIM);

  // v^T from strided v view (cols 4096..6143 of qkv) ; vt overwrites Wq_t
  transpose_bf<<<dim3(D_DIM / 64, T_DIM / 64), blk, 0, stream>>>(
      qkv_bf + 2 * D_DIM, vt_bf, 3 * D_DIM);

  // flash masked attention (q = qkv cols 0..2047, k = cols 2048..4095)
  flash_attn<<<dim3(T_DIM / 128, H_N), blk, 0, stream>>>(
      qkv_bf, qkv_bf + D_DIM, vt_bf, maskbits, attn_bf, 3 * D_DIM);

  // output projection -> f32
  gemm_bt<0><<<dim3(D_DIM / 128, T_DIM / 128), blk, 0, stream>>>(
      attn_bf, Wo_t, out, T_DIM, D_DIM, D_DIM);
}